// Round 10
// baseline (134.695 us; speedup 1.0000x reference)
//
#include <hip/hip_runtime.h>
#include <hip/hip_bf16.h>
#include <float.h>

#define NN 50000
#define KNB 32
#define INC 128
#define HC 64
#define EDD 32
#define H2C 128
#define NBLK 782    // ceil(50000/64)

typedef __attribute__((ext_vector_type(8))) short bf16x8;
typedef __attribute__((ext_vector_type(4))) float f32x4;
typedef __attribute__((ext_vector_type(4))) _Float16 f16x4;

__device__ __forceinline__ short f2bf(float f) {
    unsigned u = __builtin_bit_cast(unsigned, f);
    u += 0x7fffu + ((u >> 16) & 1u);          // RTNE
    return (short)(u >> 16);
}
__device__ __forceinline__ float bf2f(short h) {
    unsigned u = ((unsigned)(unsigned short)h) << 16;
    return __builtin_bit_cast(float, u);
}

// pack 8 f32 -> bf16x8 with v_cvt_pk_bf16_f32 (RTNE, 4 instructions)
__device__ __forceinline__ bf16x8 pack8_bf16(const float* av) {
    union { unsigned u[4]; bf16x8 v; } r;
    #pragma unroll
    for (int w = 0; w < 4; ++w) {
        asm("v_cvt_pk_bf16_f32 %0, %1, %2"
            : "=v"(r.u[w]) : "v"(av[2 * w]), "v"(av[2 * w + 1]));
    }
    return r.v;
}

// ---------------------------------------------------------------------------
// K0: pre-convert weights to fragment-ordered bf16 buffers.
// ---------------------------------------------------------------------------
__global__ __launch_bounds__(256) void k_prep(
    const float* __restrict__ w_src, const float* __restrict__ w_dst,
    const float* __restrict__ w1, const float* __restrict__ w2,
    const float* __restrict__ w_edge,
    short* __restrict__ pAhi, short* __restrict__ pAlo,
    short* __restrict__ p1hi, short* __restrict__ p1lo,
    short* __restrict__ p2hi, short* __restrict__ p2lo,
    short* __restrict__ pE)
{
    const int tid = blockIdx.x * 256 + threadIdx.x;
    const int nT  = gridDim.x * 256;
    for (int idx = tid; idx < 16384; idx += nT) {
        int kt = (idx >> 12) & 3, nt = (idx >> 9) & 7, lane = (idx >> 3) & 63, j = idx & 7;
        int lr = lane & 15, lg = lane >> 4;
        int ch = nt * 16 + lr, k = kt * 32 + lg * 8 + j;
        float f = (ch < 64) ? w_src[ch * 128 + k] : w_dst[(ch - 64) * 128 + k];
        short hi = f2bf(f);
        pAhi[idx] = hi; pAlo[idx] = f2bf(f - bf2f(hi));
    }
    for (int idx = tid; idx < 8192; idx += nT) {
        int kt = (idx >> 12) & 1, nt = (idx >> 9) & 7, lane = (idx >> 3) & 63, j = idx & 7;
        int lr = lane & 15, lg = lane >> 4;
        int ch = nt * 16 + lr, k = kt * 32 + lg * 8 + j;
        float f = w1[ch * 64 + k];
        short hi = f2bf(f);
        p1hi[idx] = hi; p1lo[idx] = f2bf(f - bf2f(hi));
    }
    for (int idx = tid; idx < 8192; idx += nT) {
        int kt = (idx >> 11) & 3, nt = (idx >> 9) & 3, lane = (idx >> 3) & 63, j = idx & 7;
        int lr = lane & 15, lg = lane >> 4;
        int ch = nt * 16 + lr, k = kt * 32 + lg * 8 + j;
        float f = w2[ch * 128 + k];
        short hi = f2bf(f);
        p2hi[idx] = hi; p2lo[idx] = f2bf(f - bf2f(hi));
    }
    for (int idx = tid; idx < 2048; idx += nT) {
        int nt = (idx >> 9) & 3, lane = (idx >> 3) & 63, j = idx & 7;
        int lr = lane & 15, lg = lane >> 4;
        int ch = nt * 16 + lr, k = lg * 8 + j;
        pE[idx] = f2bf(w_edge[ch * EDD + k]);
    }
}

__device__ __forceinline__ void split8(const float* av, bf16x8& ahi, bf16x8& alo) {
    #pragma unroll
    for (int j = 0; j < 8; ++j) {
        short h = f2bf(av[j]);
        ahi[j] = h;
        alo[j] = f2bf(av[j] - bf2f(h));
    }
}

// ---------------------------------------------------------------------------
// K1 (MFMA): [srcPh|dstf] = x @ [w_src;w_dst].T ; srcPh stored PERMUTED fp16:
// srcPh[node*64 + lr*4 + nt] = src_ch[nt*16+lr]  (row = 128B)
// ---------------------------------------------------------------------------
__global__ __launch_bounds__(256) void k_lin1(
    const float* __restrict__ x, const short* __restrict__ pAhi,
    const short* __restrict__ pAlo, _Float16* __restrict__ srcPh,
    float* __restrict__ dstf)
{
    const int lane = threadIdx.x & 63, wave = threadIdx.x >> 6;
    const int lr = lane & 15, lg = lane >> 4;
    const int nb = blockIdx.x * 64 + wave * 16;
    const bf16x8* Bh = (const bf16x8*)pAhi;
    const bf16x8* Bl = (const bf16x8*)pAlo;
    int row = nb + lr; if (row > NN - 1) row = NN - 1;

    f32x4 acc[8];
    #pragma unroll
    for (int i = 0; i < 8; ++i) acc[i] = (f32x4){0.f, 0.f, 0.f, 0.f};

    #pragma unroll
    for (int kt = 0; kt < 4; ++kt) {
        const float* ap = x + (size_t)row * INC + kt * 32 + lg * 8;
        float4 a0 = *(const float4*)ap, a1 = *(const float4*)(ap + 4);
        float av[8] = {a0.x, a0.y, a0.z, a0.w, a1.x, a1.y, a1.z, a1.w};
        bf16x8 ahi, alo;
        split8(av, ahi, alo);
        #pragma unroll
        for (int nt = 0; nt < 8; ++nt) {
            bf16x8 bh = Bh[(kt * 8 + nt) * 64 + lane];
            bf16x8 bl = Bl[(kt * 8 + nt) * 64 + lane];
            acc[nt] = __builtin_amdgcn_mfma_f32_16x16x32_bf16(ahi, bl, acc[nt], 0, 0, 0);
            acc[nt] = __builtin_amdgcn_mfma_f32_16x16x32_bf16(alo, bh, acc[nt], 0, 0, 0);
            acc[nt] = __builtin_amdgcn_mfma_f32_16x16x32_bf16(ahi, bh, acc[nt], 0, 0, 0);
        }
    }
    #pragma unroll
    for (int nt = 0; nt < 8; ++nt)
        #pragma unroll
        for (int q = 0; q < 4; ++q) {
            int node = nb + lg * 4 + q;
            if (node < NN) {
                float v = acc[nt][q];
                if (nt < 4) srcPh[node * HC + lr * 4 + nt] = (_Float16)v;  // permuted fp16
                else        dstf[node * HC + (nt - 4) * 16 + lr] = v;
            }
        }
}

// ---------------------------------------------------------------------------
// K2 (MFMA, 2 waves per node): each wave handles 16 edges (mt half) -> half
// the serial gather chain per wave, 2x wave parallelism. Cross-wave softmax
// combine via 1KB LDS + one __syncthreads. Block = 4 waves = 2 nodes.
// ---------------------------------------------------------------------------
__global__ __launch_bounds__(256) void k_edge_agg_mfma(
    const _Float16* __restrict__ srcPh, const float* __restrict__ dstf,
    const float* __restrict__ edge_attr, const short* __restrict__ pE,
    const int* __restrict__ esrc, const int* __restrict__ nbr,
    float* __restrict__ outf)
{
    __shared__ float sered[2][2][64];
    __shared__ float wsred[2][2][64];

    const int lane = threadIdx.x & 63;
    const int wave = threadIdx.x >> 6;
    const int nl   = wave >> 1;            // node within block (0,1)
    const int mt   = wave & 1;             // edge half (0: edges 0-15, 1: 16-31)
    const int node = blockIdx.x * 2 + nl;  // grid 25000 * 2 = 50000
    const int lr = lane & 15, lg = lane >> 4;

    // esrc slots for this wave's 4 edges per lane
    int4 sv = *(const int4*)&esrc[node * KNB + mt * 16 + lg * 4];

    // validity (only matters for mt=1; deg >= 16 guaranteed)
    int nbv = nbr[node * KNB + 16 + (lane & 15)];
    float d = (mt == 0) ? dstf[node * HC + lane] : 0.f;

    // B fragments (prepped bf16, raw 16B loads)
    const bf16x8* Bp = (const bf16x8*)pE;
    bf16x8 bfrag[4];
    #pragma unroll
    for (int nt = 0; nt < 4; ++nt) bfrag[nt] = Bp[nt * 64 + lane];

    // attr rows mt*16+lr (nontemporal stream)
    const f32x4* ab = (const f32x4*)(edge_attr + (size_t)node * KNB * EDD);
    int aoff = ((mt * 16 + lr) * EDD + lg * 8) >> 2;
    f32x4 at0 = __builtin_nontemporal_load(ab + aoff);
    f32x4 at1 = __builtin_nontemporal_load(ab + aoff + 1);

    // fp16 gathers (4 per lane, 32-bit offsets)
    int iv[4] = {sv.x, sv.y, sv.z, sv.w};
    f16x4 xj[4];
    #pragma unroll
    for (int r = 0; r < 4; ++r)
        xj[r] = *(const f16x4*)(srcPh + (((unsigned)iv[r] << 6) + lr * 4));

    unsigned vmask = (unsigned)__ballot((lane < 16) && (nbv >= 0));  // bits 0..15 = edges 16..31

    // attr -> bf16 A fragment via cvt_pk
    float av[8] = {at0[0], at0[1], at0[2], at0[3], at1[0], at1[1], at1[2], at1[3]};
    bf16x8 afrag = pack8_bf16(av);

    // projection: p[nt][r] = P[mt*16 + lg*4 + r][16nt + lr]
    f32x4 p[4];
    #pragma unroll
    for (int nt = 0; nt < 4; ++nt) {
        f32x4 z = {0.f, 0.f, 0.f, 0.f};
        p[nt] = __builtin_amdgcn_mfma_f32_16x16x32_bf16(afrag, bfrag[nt], z, 0, 0, 0);
    }

    float vf[4];
    #pragma unroll
    for (int r = 0; r < 4; ++r)
        vf[r] = (mt == 0) ? 1.f : (((vmask >> (lg * 4 + r)) & 1u) ? 1.f : 0.f);

    // partial softmax sums over this wave's 16 edges (no max-subtract)
    float se[4], ws[4];
    #pragma unroll
    for (int nt = 0; nt < 4; ++nt) {
        float s = 0.f, w = 0.f;
        #pragma unroll
        for (int r = 0; r < 4; ++r) {
            float m = fmaxf(p[nt][r] + (float)xj[r][nt], 0.f);
            float t = __expf(m) * vf[r];
            s += t;
            w = fmaf(m, t, w);
        }
        s += __shfl_xor(s, 16, 64); w += __shfl_xor(w, 16, 64);
        s += __shfl_xor(s, 32, 64); w += __shfl_xor(w, 32, 64);
        se[nt] = s; ws[nt] = w;
    }

    // lane writes channel == lane (nt = lg): constant-index selects
    float s01 = (lg & 1) ? se[1] : se[0];
    float s23 = (lg & 1) ? se[3] : se[2];
    float ssel = (lg & 2) ? s23 : s01;
    float w01 = (lg & 1) ? ws[1] : ws[0];
    float w23 = (lg & 1) ? ws[3] : ws[2];
    float wsel = (lg & 2) ? w23 : w01;
    sered[nl][mt][lane] = ssel;
    wsred[nl][mt][lane] = wsel;
    __syncthreads();

    if (mt == 0) {
        float seT = sered[nl][0][lane] + sered[nl][1][lane];
        float wsT = wsred[nl][0][lane] + wsred[nl][1][lane];
        float res = wsT * __builtin_amdgcn_rcpf(seT + 1e-16f);
        outf[node * HC + lane] = res + d + 1e-7f;
    }
}

// ---------------------------------------------------------------------------
// K3 (MFMA): h = out @ w1.T  [N,64]->[N,128]  + per-block BN partials.
// ---------------------------------------------------------------------------
__global__ __launch_bounds__(256) void k_lin2(
    const float* __restrict__ outf, const short* __restrict__ p1hi,
    const short* __restrict__ p1lo, float* __restrict__ h,
    float* __restrict__ partials)
{
    __shared__ float ps[128 * 16], pq[128 * 16];
    const int t = threadIdx.x;
    const int lane = t & 63, wave = t >> 6;
    const int lr = lane & 15, lg = lane >> 4;
    const int nb = blockIdx.x * 64 + wave * 16;
    const bf16x8* Bh = (const bf16x8*)p1hi;
    const bf16x8* Bl = (const bf16x8*)p1lo;
    int row = nb + lr; if (row > NN - 1) row = NN - 1;

    f32x4 acc[8];
    #pragma unroll
    for (int i = 0; i < 8; ++i) acc[i] = (f32x4){0.f, 0.f, 0.f, 0.f};

    #pragma unroll
    for (int kt = 0; kt < 2; ++kt) {
        const float* ap = outf + (size_t)row * HC + kt * 32 + lg * 8;
        float4 a0 = *(const float4*)ap, a1 = *(const float4*)(ap + 4);
        float av[8] = {a0.x, a0.y, a0.z, a0.w, a1.x, a1.y, a1.z, a1.w};
        bf16x8 ahi, alo;
        split8(av, ahi, alo);
        #pragma unroll
        for (int nt = 0; nt < 8; ++nt) {
            bf16x8 bh = Bh[(kt * 8 + nt) * 64 + lane];
            bf16x8 bl = Bl[(kt * 8 + nt) * 64 + lane];
            acc[nt] = __builtin_amdgcn_mfma_f32_16x16x32_bf16(ahi, bl, acc[nt], 0, 0, 0);
            acc[nt] = __builtin_amdgcn_mfma_f32_16x16x32_bf16(alo, bh, acc[nt], 0, 0, 0);
            acc[nt] = __builtin_amdgcn_mfma_f32_16x16x32_bf16(ahi, bh, acc[nt], 0, 0, 0);
        }
    }

    #pragma unroll
    for (int nt = 0; nt < 8; ++nt) {
        float s = 0.f, q = 0.f;
        #pragma unroll
        for (int qq = 0; qq < 4; ++qq) {
            int node = nb + lg * 4 + qq;
            float v = acc[nt][qq];
            if (node < NN) {
                h[node * H2C + nt * 16 + lr] = v;
                s += v;
                q += v * v;
            }
        }
        ps[(nt * 16 + lr) * 16 + wave * 4 + lg] = s;
        pq[(nt * 16 + lr) * 16 + wave * 4 + lg] = q;
    }
    __syncthreads();
    if (t < 128) {
        float s = 0.f, q = 0.f;
        #pragma unroll
        for (int i = 0; i < 16; ++i) { s += ps[t * 16 + i]; q += pq[t * 16 + i]; }
        partials[blockIdx.x * 256 + t]       = s;
        partials[blockIdx.x * 256 + 128 + t] = q;
    }
}

// ---------------------------------------------------------------------------
// K4: reduce partials -> BN scale/bias (1024 threads, vectorized).
// ---------------------------------------------------------------------------
__global__ __launch_bounds__(1024) void k_bn_finalize(
    const float* __restrict__ partials, int nblk,
    const float* __restrict__ gamma, const float* __restrict__ beta,
    float* __restrict__ sb)
{
    const int t = threadIdx.x;
    const int f = t & 63;
    const int g = t >> 6;

    float4 acc = {0.f, 0.f, 0.f, 0.f};
    for (int b = g; b < nblk; b += 16) {
        float4 v = *(const float4*)&partials[b * 256 + f * 4];
        acc.x += v.x; acc.y += v.y; acc.z += v.z; acc.w += v.w;
    }

    __shared__ __align__(16) float4 red[16][64];
    red[g][f] = acc;
    __syncthreads();
    #pragma unroll
    for (int s = 8; s > 0; s >>= 1) {
        if (g < s) {
            float4 o = red[g + s][f];
            acc.x += o.x; acc.y += o.y; acc.z += o.z; acc.w += o.w;
            red[g][f] = acc;
        }
        __syncthreads();
    }

    if (t < 128) {
        const float* row = (const float*)&red[0][0];
        float s = row[t];
        float q = row[128 + t];
        float mean = s / (float)NN;
        float var  = q / (float)NN - mean * mean;
        float scale = gamma[t] * rsqrtf(var + 1e-5f);
        float bias  = beta[t] - mean * scale;
        sb[t]       = scale;
        sb[128 + t] = bias;
    }
}

// ---------------------------------------------------------------------------
// K5 (MFMA): out2 = relu(h*scale+bias) @ w2.T  [N,128]->[N,64]
// ---------------------------------------------------------------------------
__global__ __launch_bounds__(256) void k_lin3(
    const float* __restrict__ h, const short* __restrict__ p2hi,
    const short* __restrict__ p2lo, const float* __restrict__ sb,
    float* __restrict__ out)
{
    const int lane = threadIdx.x & 63, wave = threadIdx.x >> 6;
    const int lr = lane & 15, lg = lane >> 4;
    const int nb = blockIdx.x * 64 + wave * 16;
    const bf16x8* Bh = (const bf16x8*)p2hi;
    const bf16x8* Bl = (const bf16x8*)p2lo;
    int row = nb + lr; if (row > NN - 1) row = NN - 1;

    f32x4 acc[4];
    #pragma unroll
    for (int i = 0; i < 4; ++i) acc[i] = (f32x4){0.f, 0.f, 0.f, 0.f};

    #pragma unroll
    for (int kt = 0; kt < 4; ++kt) {
        const int k0 = kt * 32 + lg * 8;
        float4 sc0 = *(const float4*)&sb[k0],       sc1 = *(const float4*)&sb[k0 + 4];
        float4 bi0 = *(const float4*)&sb[128 + k0], bi1 = *(const float4*)&sb[128 + k0 + 4];
        const float* ap = h + (size_t)row * H2C + k0;
        float4 a0 = *(const float4*)ap, a1 = *(const float4*)(ap + 4);
        float av[8]  = {a0.x, a0.y, a0.z, a0.w, a1.x, a1.y, a1.z, a1.w};
        float scv[8] = {sc0.x, sc0.y, sc0.z, sc0.w, sc1.x, sc1.y, sc1.z, sc1.w};
        float biv[8] = {bi0.x, bi0.y, bi0.z, bi0.w, bi1.x, bi1.y, bi1.z, bi1.w};
        float rv[8];
        #pragma unroll
        for (int j = 0; j < 8; ++j) {
            float v = av[j] * scv[j] + biv[j];
            rv[j] = v > 0.f ? v : 0.f;
        }
        bf16x8 ahi, alo;
        split8(rv, ahi, alo);
        #pragma unroll
        for (int nt = 0; nt < 4; ++nt) {
            bf16x8 bh = Bh[(kt * 4 + nt) * 64 + lane];
            bf16x8 bl = Bl[(kt * 4 + nt) * 64 + lane];
            acc[nt] = __builtin_amdgcn_mfma_f32_16x16x32_bf16(ahi, bl, acc[nt], 0, 0, 0);
            acc[nt] = __builtin_amdgcn_mfma_f32_16x16x32_bf16(alo, bh, acc[nt], 0, 0, 0);
            acc[nt] = __builtin_amdgcn_mfma_f32_16x16x32_bf16(ahi, bh, acc[nt], 0, 0, 0);
        }
    }
    #pragma unroll
    for (int nt = 0; nt < 4; ++nt)
        #pragma unroll
        for (int q = 0; q < 4; ++q) {
            int node = nb + lg * 4 + q;
            if (node < NN) out[node * HC + nt * 16 + lr] = acc[nt][q];
        }
}

// ---------------------------------------------------------------------------
extern "C" void kernel_launch(void* const* d_in, const int* in_sizes, int n_in,
                              void* d_out, int out_size, void* d_ws, size_t ws_size,
                              hipStream_t stream) {
    const float* x         = (const float*)d_in[0];
    const float* edge_attr = (const float*)d_in[1];
    const float* w_src     = (const float*)d_in[2];
    const float* w_dst     = (const float*)d_in[3];
    const float* w_edge    = (const float*)d_in[4];
    const float* w1        = (const float*)d_in[5];
    const float* gamma     = (const float*)d_in[6];
    const float* beta      = (const float*)d_in[7];
    const float* w2        = (const float*)d_in[8];
    const int*   eidx      = (const int*)d_in[9];    // [2][E], row 0 = src
    const int*   nbr       = (const int*)d_in[10];   // [N][K]

    float* ws   = (float*)d_ws;
    _Float16* srcPh = (_Float16*)ws;     // N*64 fp16 (permuted)
    float* dstf = ws + 3200000;          // N*64
    float* outf = ws + 6400000;          // N*64
    float* h    = ws + 9600000;          // N*128
    float* part = ws + 16000000;         // NBLK*256
    float* sb   = ws + 16250000;         // 256
    short* sp   = (short*)(ws + 16300000);
    short* pAhi = sp;                    // 16384 shorts
    short* pAlo = sp + 16384;
    short* p1hi = sp + 32768;            // 8192
    short* p1lo = sp + 40960;
    short* p2hi = sp + 49152;            // 8192
    short* p2lo = sp + 57344;
    short* pE   = sp + 65536;            // 2048

    hipLaunchKernelGGL(k_prep,          dim3(32),    dim3(256),  0, stream,
                       w_src, w_dst, w1, w2, w_edge,
                       pAhi, pAlo, p1hi, p1lo, p2hi, p2lo, pE);
    hipLaunchKernelGGL(k_lin1,          dim3(NBLK),  dim3(256),  0, stream,
                       x, pAhi, pAlo, srcPh, dstf);
    hipLaunchKernelGGL(k_edge_agg_mfma, dim3(25000), dim3(256),  0, stream,
                       srcPh, dstf, edge_attr, pE, eidx, nbr, outf);
    hipLaunchKernelGGL(k_lin2,          dim3(NBLK),  dim3(256),  0, stream,
                       outf, p1hi, p1lo, h, part);
    hipLaunchKernelGGL(k_bn_finalize,   dim3(1),     dim3(1024), 0, stream,
                       part, NBLK, gamma, beta, sb);
    hipLaunchKernelGGL(k_lin3,          dim3(NBLK),  dim3(256),  0, stream,
                       h, p2hi, p2lo, sb, (float*)d_out);
}

// Round 11
// 132.917 us; speedup vs baseline: 1.0134x; 1.0134x over previous
//
#include <hip/hip_runtime.h>
#include <hip/hip_bf16.h>
#include <float.h>

#define NN 50000
#define KNB 32
#define INC 128
#define HC 64
#define EDD 32
#define H2C 128
#define NBLK 782    // ceil(50000/64)

typedef __attribute__((ext_vector_type(8))) short bf16x8;
typedef __attribute__((ext_vector_type(4))) float f32x4;
typedef __attribute__((ext_vector_type(4))) _Float16 f16x4;

__device__ __forceinline__ short f2bf(float f) {
    unsigned u = __builtin_bit_cast(unsigned, f);
    u += 0x7fffu + ((u >> 16) & 1u);          // RTNE
    return (short)(u >> 16);
}
__device__ __forceinline__ float bf2f(short h) {
    unsigned u = ((unsigned)(unsigned short)h) << 16;
    return __builtin_bit_cast(float, u);
}

// pack 8 f32 -> bf16x8 with v_cvt_pk_bf16_f32 (RTNE, 4 instructions)
__device__ __forceinline__ bf16x8 pack8_bf16(const float* av) {
    union { unsigned u[4]; bf16x8 v; } r;
    #pragma unroll
    for (int w = 0; w < 4; ++w) {
        asm("v_cvt_pk_bf16_f32 %0, %1, %2"
            : "=v"(r.u[w]) : "v"(av[2 * w]), "v"(av[2 * w + 1]));
    }
    return r.v;
}

// hi/lo split via cvt_pk: hi = RTNE(bf16), lo = RTNE(f - hi). 24 VALU vs 40.
__device__ __forceinline__ void split8(const float* av, bf16x8& ahi, bf16x8& alo) {
    union { unsigned u[4]; bf16x8 v; } H;
    float lo[8];
    #pragma unroll
    for (int w = 0; w < 4; ++w) {
        asm("v_cvt_pk_bf16_f32 %0, %1, %2"
            : "=v"(H.u[w]) : "v"(av[2 * w]), "v"(av[2 * w + 1]));
        float h0 = __builtin_bit_cast(float, H.u[w] << 16);
        float h1 = __builtin_bit_cast(float, H.u[w] & 0xffff0000u);
        lo[2 * w]     = av[2 * w]     - h0;
        lo[2 * w + 1] = av[2 * w + 1] - h1;
    }
    ahi = H.v;
    alo = pack8_bf16(lo);
}

// ---------------------------------------------------------------------------
// K0: pre-convert weights to fragment-ordered bf16 buffers.
// ---------------------------------------------------------------------------
__global__ __launch_bounds__(256) void k_prep(
    const float* __restrict__ w_src, const float* __restrict__ w_dst,
    const float* __restrict__ w1, const float* __restrict__ w2,
    const float* __restrict__ w_edge,
    short* __restrict__ pAhi, short* __restrict__ pAlo,
    short* __restrict__ p1hi, short* __restrict__ p1lo,
    short* __restrict__ p2hi, short* __restrict__ p2lo,
    short* __restrict__ pE)
{
    const int tid = blockIdx.x * 256 + threadIdx.x;
    const int nT  = gridDim.x * 256;
    for (int idx = tid; idx < 16384; idx += nT) {
        int kt = (idx >> 12) & 3, nt = (idx >> 9) & 7, lane = (idx >> 3) & 63, j = idx & 7;
        int lr = lane & 15, lg = lane >> 4;
        int ch = nt * 16 + lr, k = kt * 32 + lg * 8 + j;
        float f = (ch < 64) ? w_src[ch * 128 + k] : w_dst[(ch - 64) * 128 + k];
        short hi = f2bf(f);
        pAhi[idx] = hi; pAlo[idx] = f2bf(f - bf2f(hi));
    }
    for (int idx = tid; idx < 8192; idx += nT) {
        int kt = (idx >> 12) & 1, nt = (idx >> 9) & 7, lane = (idx >> 3) & 63, j = idx & 7;
        int lr = lane & 15, lg = lane >> 4;
        int ch = nt * 16 + lr, k = kt * 32 + lg * 8 + j;
        float f = w1[ch * 64 + k];
        short hi = f2bf(f);
        p1hi[idx] = hi; p1lo[idx] = f2bf(f - bf2f(hi));
    }
    for (int idx = tid; idx < 8192; idx += nT) {
        int kt = (idx >> 11) & 3, nt = (idx >> 9) & 3, lane = (idx >> 3) & 63, j = idx & 7;
        int lr = lane & 15, lg = lane >> 4;
        int ch = nt * 16 + lr, k = kt * 32 + lg * 8 + j;
        float f = w2[ch * 128 + k];
        short hi = f2bf(f);
        p2hi[idx] = hi; p2lo[idx] = f2bf(f - bf2f(hi));
    }
    for (int idx = tid; idx < 2048; idx += nT) {
        int nt = (idx >> 9) & 3, lane = (idx >> 3) & 63, j = idx & 7;
        int lr = lane & 15, lg = lane >> 4;
        int ch = nt * 16 + lr, k = lg * 8 + j;
        pE[idx] = f2bf(w_edge[ch * EDD + k]);
    }
}

// ---------------------------------------------------------------------------
// K1 (MFMA): [srcPh|dstf] = x @ [w_src;w_dst].T ; srcPh stored PERMUTED fp16:
// srcPh[node*64 + lr*4 + nt] = src_ch[nt*16+lr]  (row = 128B)
// ---------------------------------------------------------------------------
__global__ __launch_bounds__(256) void k_lin1(
    const float* __restrict__ x, const short* __restrict__ pAhi,
    const short* __restrict__ pAlo, _Float16* __restrict__ srcPh,
    float* __restrict__ dstf)
{
    const int lane = threadIdx.x & 63, wave = threadIdx.x >> 6;
    const int lr = lane & 15, lg = lane >> 4;
    const int nb = blockIdx.x * 64 + wave * 16;
    const bf16x8* Bh = (const bf16x8*)pAhi;
    const bf16x8* Bl = (const bf16x8*)pAlo;
    int row = nb + lr; if (row > NN - 1) row = NN - 1;

    f32x4 acc[8];
    #pragma unroll
    for (int i = 0; i < 8; ++i) acc[i] = (f32x4){0.f, 0.f, 0.f, 0.f};

    #pragma unroll
    for (int kt = 0; kt < 4; ++kt) {
        const float* ap = x + (size_t)row * INC + kt * 32 + lg * 8;
        float4 a0 = *(const float4*)ap, a1 = *(const float4*)(ap + 4);
        float av[8] = {a0.x, a0.y, a0.z, a0.w, a1.x, a1.y, a1.z, a1.w};
        bf16x8 ahi, alo;
        split8(av, ahi, alo);
        #pragma unroll
        for (int nt = 0; nt < 8; ++nt) {
            bf16x8 bh = Bh[(kt * 8 + nt) * 64 + lane];
            bf16x8 bl = Bl[(kt * 8 + nt) * 64 + lane];
            acc[nt] = __builtin_amdgcn_mfma_f32_16x16x32_bf16(ahi, bl, acc[nt], 0, 0, 0);
            acc[nt] = __builtin_amdgcn_mfma_f32_16x16x32_bf16(alo, bh, acc[nt], 0, 0, 0);
            acc[nt] = __builtin_amdgcn_mfma_f32_16x16x32_bf16(ahi, bh, acc[nt], 0, 0, 0);
        }
    }
    #pragma unroll
    for (int nt = 0; nt < 8; ++nt)
        #pragma unroll
        for (int q = 0; q < 4; ++q) {
            int node = nb + lg * 4 + q;
            if (node < NN) {
                float v = acc[nt][q];
                if (nt < 4) srcPh[node * HC + lr * 4 + nt] = (_Float16)v;  // permuted fp16
                else        dstf[node * HC + (nt - 4) * 16 + lr] = v;
            }
        }
}

// ---------------------------------------------------------------------------
// K2 (MFMA, simple 1-node/wave, VALU-diet; best-measured R9 form).
// ---------------------------------------------------------------------------
__global__ __launch_bounds__(256) void k_edge_agg_mfma(
    const _Float16* __restrict__ srcPh, const float* __restrict__ dstf,
    const float* __restrict__ edge_attr, const short* __restrict__ pE,
    const int* __restrict__ esrc, const int* __restrict__ nbr,
    float* __restrict__ outf)
{
    const int lane = threadIdx.x & 63;
    const int wave = threadIdx.x >> 6;
    const int n    = blockIdx.x * 4 + wave;    // 12500 * 4 = 50000
    const int lr = lane & 15, lg = lane >> 4;

    // esrc slots for this lane's 8 edges (2 x int4)
    int4 s0 = *(const int4*)&esrc[n * KNB + lg * 4];
    int4 s1 = *(const int4*)&esrc[n * KNB + 16 + lg * 4];
    int nbv   = nbr[n * KNB + (lane & 31)];
    float d   = dstf[n * HC + lane];

    // B fragments (prepped bf16, raw 16B loads)
    const bf16x8* Bp = (const bf16x8*)pE;
    bf16x8 bfrag[4];
    #pragma unroll
    for (int nt = 0; nt < 4; ++nt) bfrag[nt] = Bp[nt * 64 + lane];

    // attr tile loads (nontemporal; single-use stream)
    const f32x4* ab = (const f32x4*)(edge_attr + (size_t)n * KNB * EDD);
    f32x4 at[4];
    #pragma unroll
    for (int mt = 0; mt < 2; ++mt) {
        int off = ((mt * 16 + lr) * EDD + lg * 8) >> 2;
        at[mt * 2]     = __builtin_nontemporal_load(ab + off);
        at[mt * 2 + 1] = __builtin_nontemporal_load(ab + off + 1);
    }

    // fp16 gathers, 32-bit offsets (idx*64 elements, +lr*4)
    int i0[4] = {s0.x, s0.y, s0.z, s0.w};
    int i1[4] = {s1.x, s1.y, s1.z, s1.w};
    f16x4 xj0[4], xj1[4];
    #pragma unroll
    for (int r = 0; r < 4; ++r)
        xj0[r] = *(const f16x4*)(srcPh + (((unsigned)i0[r] << 6) + lr * 4));
    #pragma unroll
    for (int r = 0; r < 4; ++r)
        xj1[r] = *(const f16x4*)(srcPh + (((unsigned)i1[r] << 6) + lr * 4));

    unsigned vmask = (unsigned)__ballot((lane < 32) && (nbv >= 0));

    // attr -> bf16 A-fragments via cvt_pk (RTNE, 4 ops per fragment)
    bf16x8 afrag[2];
    #pragma unroll
    for (int mt = 0; mt < 2; ++mt) {
        float av[8] = {at[mt*2][0], at[mt*2][1], at[mt*2][2], at[mt*2][3],
                       at[mt*2+1][0], at[mt*2+1][1], at[mt*2+1][2], at[mt*2+1][3]};
        afrag[mt] = pack8_bf16(av);
    }

    // projection: p[mt][nt][r] = P[16mt + lg*4 + r][16nt + lr]
    f32x4 p[2][4];
    #pragma unroll
    for (int mt = 0; mt < 2; ++mt)
        #pragma unroll
        for (int nt = 0; nt < 4; ++nt) {
            f32x4 z = {0.f, 0.f, 0.f, 0.f};
            p[mt][nt] = __builtin_amdgcn_mfma_f32_16x16x32_bf16(
                afrag[mt], bfrag[nt], z, 0, 0, 0);
        }

    // validity only for edges 16..31 (deg >= 16 guaranteed)
    float vf[4];
    #pragma unroll
    for (int r = 0; r < 4; ++r)
        vf[r] = ((vmask >> (16 + lg * 4 + r)) & 1u) ? 1.f : 0.f;

    // softmax-weighted mean (no max-subtract; eps folded to the end)
    float res[4];
    #pragma unroll
    for (int nt = 0; nt < 4; ++nt) {
        float se = 0.f, ws = 0.f;
        #pragma unroll
        for (int r = 0; r < 4; ++r) {
            float m = fmaxf(p[0][nt][r] + (float)xj0[r][nt], 0.f);
            float t = __expf(m);
            se += t;
            ws = fmaf(m, t, ws);
        }
        #pragma unroll
        for (int r = 0; r < 4; ++r) {
            float m = fmaxf(p[1][nt][r] + (float)xj1[r][nt], 0.f);
            float t = __expf(m) * vf[r];
            se += t;
            ws = fmaf(m, t, ws);
        }
        se += __shfl_xor(se, 16, 64); ws += __shfl_xor(ws, 16, 64);
        se += __shfl_xor(se, 32, 64); ws += __shfl_xor(ws, 32, 64);
        res[nt] = ws * __builtin_amdgcn_rcpf(se + 1e-16f);
    }

    float r01 = (lg & 1) ? res[1] : res[0];
    float r23 = (lg & 1) ? res[3] : res[2];
    float rr  = (lg & 2) ? r23 : r01;
    outf[n * HC + lane] = rr + d + 1e-7f;
}

// ---------------------------------------------------------------------------
// K3 (MFMA): h = out @ w1.T  [N,64]->[N,128]  + per-block BN partials.
// ---------------------------------------------------------------------------
__global__ __launch_bounds__(256) void k_lin2(
    const float* __restrict__ outf, const short* __restrict__ p1hi,
    const short* __restrict__ p1lo, float* __restrict__ h,
    float* __restrict__ partials)
{
    __shared__ float ps[128 * 16], pq[128 * 16];
    const int t = threadIdx.x;
    const int lane = t & 63, wave = t >> 6;
    const int lr = lane & 15, lg = lane >> 4;
    const int nb = blockIdx.x * 64 + wave * 16;
    const bf16x8* Bh = (const bf16x8*)p1hi;
    const bf16x8* Bl = (const bf16x8*)p1lo;
    int row = nb + lr; if (row > NN - 1) row = NN - 1;

    f32x4 acc[8];
    #pragma unroll
    for (int i = 0; i < 8; ++i) acc[i] = (f32x4){0.f, 0.f, 0.f, 0.f};

    #pragma unroll
    for (int kt = 0; kt < 2; ++kt) {
        const float* ap = outf + (size_t)row * HC + kt * 32 + lg * 8;
        float4 a0 = *(const float4*)ap, a1 = *(const float4*)(ap + 4);
        float av[8] = {a0.x, a0.y, a0.z, a0.w, a1.x, a1.y, a1.z, a1.w};
        bf16x8 ahi, alo;
        split8(av, ahi, alo);
        #pragma unroll
        for (int nt = 0; nt < 8; ++nt) {
            bf16x8 bh = Bh[(kt * 8 + nt) * 64 + lane];
            bf16x8 bl = Bl[(kt * 8 + nt) * 64 + lane];
            acc[nt] = __builtin_amdgcn_mfma_f32_16x16x32_bf16(ahi, bl, acc[nt], 0, 0, 0);
            acc[nt] = __builtin_amdgcn_mfma_f32_16x16x32_bf16(alo, bh, acc[nt], 0, 0, 0);
            acc[nt] = __builtin_amdgcn_mfma_f32_16x16x32_bf16(ahi, bh, acc[nt], 0, 0, 0);
        }
    }

    #pragma unroll
    for (int nt = 0; nt < 8; ++nt) {
        float s = 0.f, q = 0.f;
        #pragma unroll
        for (int qq = 0; qq < 4; ++qq) {
            int node = nb + lg * 4 + qq;
            float v = acc[nt][qq];
            if (node < NN) {
                h[node * H2C + nt * 16 + lr] = v;
                s += v;
                q += v * v;
            }
        }
        ps[(nt * 16 + lr) * 16 + wave * 4 + lg] = s;
        pq[(nt * 16 + lr) * 16 + wave * 4 + lg] = q;
    }
    __syncthreads();
    if (t < 128) {
        float s = 0.f, q = 0.f;
        #pragma unroll
        for (int i = 0; i < 16; ++i) { s += ps[t * 16 + i]; q += pq[t * 16 + i]; }
        partials[blockIdx.x * 256 + t]       = s;
        partials[blockIdx.x * 256 + 128 + t] = q;
    }
}

// ---------------------------------------------------------------------------
// K4: reduce partials -> BN scale/bias (1024 threads, vectorized).
// ---------------------------------------------------------------------------
__global__ __launch_bounds__(1024) void k_bn_finalize(
    const float* __restrict__ partials, int nblk,
    const float* __restrict__ gamma, const float* __restrict__ beta,
    float* __restrict__ sb)
{
    const int t = threadIdx.x;
    const int f = t & 63;
    const int g = t >> 6;

    float4 acc = {0.f, 0.f, 0.f, 0.f};
    for (int b = g; b < nblk; b += 16) {
        float4 v = *(const float4*)&partials[b * 256 + f * 4];
        acc.x += v.x; acc.y += v.y; acc.z += v.z; acc.w += v.w;
    }

    __shared__ __align__(16) float4 red[16][64];
    red[g][f] = acc;
    __syncthreads();
    #pragma unroll
    for (int s = 8; s > 0; s >>= 1) {
        if (g < s) {
            float4 o = red[g + s][f];
            acc.x += o.x; acc.y += o.y; acc.z += o.z; acc.w += o.w;
            red[g][f] = acc;
        }
        __syncthreads();
    }

    if (t < 128) {
        const float* row = (const float*)&red[0][0];
        float s = row[t];
        float q = row[128 + t];
        float mean = s / (float)NN;
        float var  = q / (float)NN - mean * mean;
        float scale = gamma[t] * rsqrtf(var + 1e-5f);
        float bias  = beta[t] - mean * scale;
        sb[t]       = scale;
        sb[128 + t] = bias;
    }
}

// ---------------------------------------------------------------------------
// K5 (MFMA): out2 = relu(h*scale+bias) @ w2.T  [N,128]->[N,64]
// ---------------------------------------------------------------------------
__global__ __launch_bounds__(256) void k_lin3(
    const float* __restrict__ h, const short* __restrict__ p2hi,
    const short* __restrict__ p2lo, const float* __restrict__ sb,
    float* __restrict__ out)
{
    const int lane = threadIdx.x & 63, wave = threadIdx.x >> 6;
    const int lr = lane & 15, lg = lane >> 4;
    const int nb = blockIdx.x * 64 + wave * 16;
    const bf16x8* Bh = (const bf16x8*)p2hi;
    const bf16x8* Bl = (const bf16x8*)p2lo;
    int row = nb + lr; if (row > NN - 1) row = NN - 1;

    f32x4 acc[4];
    #pragma unroll
    for (int i = 0; i < 4; ++i) acc[i] = (f32x4){0.f, 0.f, 0.f, 0.f};

    #pragma unroll
    for (int kt = 0; kt < 4; ++kt) {
        const int k0 = kt * 32 + lg * 8;
        float4 sc0 = *(const float4*)&sb[k0],       sc1 = *(const float4*)&sb[k0 + 4];
        float4 bi0 = *(const float4*)&sb[128 + k0], bi1 = *(const float4*)&sb[128 + k0 + 4];
        const float* ap = h + (size_t)row * H2C + k0;
        float4 a0 = *(const float4*)ap, a1 = *(const float4*)(ap + 4);
        float av[8]  = {a0.x, a0.y, a0.z, a0.w, a1.x, a1.y, a1.z, a1.w};
        float scv[8] = {sc0.x, sc0.y, sc0.z, sc0.w, sc1.x, sc1.y, sc1.z, sc1.w};
        float biv[8] = {bi0.x, bi0.y, bi0.z, bi0.w, bi1.x, bi1.y, bi1.z, bi1.w};
        float rv[8];
        #pragma unroll
        for (int j = 0; j < 8; ++j) {
            float v = av[j] * scv[j] + biv[j];
            rv[j] = v > 0.f ? v : 0.f;
        }
        bf16x8 ahi, alo;
        split8(rv, ahi, alo);
        #pragma unroll
        for (int nt = 0; nt < 4; ++nt) {
            bf16x8 bh = Bh[(kt * 4 + nt) * 64 + lane];
            bf16x8 bl = Bl[(kt * 4 + nt) * 64 + lane];
            acc[nt] = __builtin_amdgcn_mfma_f32_16x16x32_bf16(ahi, bl, acc[nt], 0, 0, 0);
            acc[nt] = __builtin_amdgcn_mfma_f32_16x16x32_bf16(alo, bh, acc[nt], 0, 0, 0);
            acc[nt] = __builtin_amdgcn_mfma_f32_16x16x32_bf16(ahi, bh, acc[nt], 0, 0, 0);
        }
    }
    #pragma unroll
    for (int nt = 0; nt < 4; ++nt)
        #pragma unroll
        for (int q = 0; q < 4; ++q) {
            int node = nb + lg * 4 + q;
            if (node < NN) out[node * HC + nt * 16 + lr] = acc[nt][q];
        }
}

// ---------------------------------------------------------------------------
extern "C" void kernel_launch(void* const* d_in, const int* in_sizes, int n_in,
                              void* d_out, int out_size, void* d_ws, size_t ws_size,
                              hipStream_t stream) {
    const float* x         = (const float*)d_in[0];
    const float* edge_attr = (const float*)d_in[1];
    const float* w_src     = (const float*)d_in[2];
    const float* w_dst     = (const float*)d_in[3];
    const float* w_edge    = (const float*)d_in[4];
    const float* w1        = (const float*)d_in[5];
    const float* gamma     = (const float*)d_in[6];
    const float* beta      = (const float*)d_in[7];
    const float* w2        = (const float*)d_in[8];
    const int*   eidx      = (const int*)d_in[9];    // [2][E], row 0 = src
    const int*   nbr       = (const int*)d_in[10];   // [N][K]

    float* ws   = (float*)d_ws;
    _Float16* srcPh = (_Float16*)ws;     // N*64 fp16 (permuted)
    float* dstf = ws + 3200000;          // N*64
    float* outf = ws + 6400000;          // N*64
    float* h    = ws + 9600000;          // N*128
    float* part = ws + 16000000;         // NBLK*256
    float* sb   = ws + 16250000;         // 256
    short* sp   = (short*)(ws + 16300000);
    short* pAhi = sp;                    // 16384 shorts
    short* pAlo = sp + 16384;
    short* p1hi = sp + 32768;            // 8192
    short* p1lo = sp + 40960;
    short* p2hi = sp + 49152;            // 8192
    short* p2lo = sp + 57344;
    short* pE   = sp + 65536;            // 2048

    hipLaunchKernelGGL(k_prep,          dim3(32),    dim3(256),  0, stream,
                       w_src, w_dst, w1, w2, w_edge,
                       pAhi, pAlo, p1hi, p1lo, p2hi, p2lo, pE);
    hipLaunchKernelGGL(k_lin1,          dim3(NBLK),  dim3(256),  0, stream,
                       x, pAhi, pAlo, srcPh, dstf);
    hipLaunchKernelGGL(k_edge_agg_mfma, dim3(12500), dim3(256),  0, stream,
                       srcPh, dstf, edge_attr, pE, eidx, nbr, outf);
    hipLaunchKernelGGL(k_lin2,          dim3(NBLK),  dim3(256),  0, stream,
                       outf, p1hi, p1lo, h, part);
    hipLaunchKernelGGL(k_bn_finalize,   dim3(1),     dim3(1024), 0, stream,
                       part, NBLK, gamma, beta, sb);
    hipLaunchKernelGGL(k_lin3,          dim3(NBLK),  dim3(256),  0, stream,
                       h, p2hi, p2lo, sb, (float*)d_out);
}

// Round 12
// 131.017 us; speedup vs baseline: 1.0281x; 1.0145x over previous
//
#include <hip/hip_runtime.h>
#include <hip/hip_bf16.h>
#include <float.h>

#define NN 50000
#define KNB 32
#define INC 128
#define HC 64
#define EDD 32
#define H2C 128
#define NBLK 782    // ceil(50000/64)

typedef __attribute__((ext_vector_type(8))) short bf16x8;
typedef __attribute__((ext_vector_type(8))) unsigned short u16x8;
typedef __attribute__((ext_vector_type(4))) float f32x4;
typedef __attribute__((ext_vector_type(4))) _Float16 f16x4;

__device__ __forceinline__ short f2bf(float f) {
    unsigned u = __builtin_bit_cast(unsigned, f);
    u += 0x7fffu + ((u >> 16) & 1u);          // RTNE
    return (short)(u >> 16);
}
__device__ __forceinline__ float bf2f(unsigned short h) {
    unsigned u = ((unsigned)h) << 16;
    return __builtin_bit_cast(float, u);
}

// pack 8 f32 -> bf16x8 with v_cvt_pk_bf16_f32 (RTNE, 4 instructions)
__device__ __forceinline__ bf16x8 pack8_bf16(const float* av) {
    union { unsigned u[4]; bf16x8 v; } r;
    #pragma unroll
    for (int w = 0; w < 4; ++w) {
        asm("v_cvt_pk_bf16_f32 %0, %1, %2"
            : "=v"(r.u[w]) : "v"(av[2 * w]), "v"(av[2 * w + 1]));
    }
    return r.v;
}

// hi/lo split via cvt_pk: hi = RTNE(bf16), lo = RTNE(f - hi).
__device__ __forceinline__ void split8(const float* av, bf16x8& ahi, bf16x8& alo) {
    union { unsigned u[4]; bf16x8 v; } H;
    float lo[8];
    #pragma unroll
    for (int w = 0; w < 4; ++w) {
        asm("v_cvt_pk_bf16_f32 %0, %1, %2"
            : "=v"(H.u[w]) : "v"(av[2 * w]), "v"(av[2 * w + 1]));
        float h0 = __builtin_bit_cast(float, H.u[w] << 16);
        float h1 = __builtin_bit_cast(float, H.u[w] & 0xffff0000u);
        lo[2 * w]     = av[2 * w]     - h0;
        lo[2 * w + 1] = av[2 * w + 1] - h1;
    }
    ahi = H.v;
    alo = pack8_bf16(lo);
}

// ---------------------------------------------------------------------------
// K0: pre-convert weights to fragment-ordered bf16 buffers + validity masks.
// ---------------------------------------------------------------------------
__global__ __launch_bounds__(256) void k_prep(
    const float* __restrict__ w_src, const float* __restrict__ w_dst,
    const float* __restrict__ w1, const float* __restrict__ w2,
    const float* __restrict__ w_edge, const int* __restrict__ nbr,
    short* __restrict__ pAhi, short* __restrict__ pAlo,
    short* __restrict__ p1hi, short* __restrict__ p1lo,
    short* __restrict__ p2hi, short* __restrict__ p2lo,
    short* __restrict__ pE, unsigned* __restrict__ vmsk)
{
    const int tid = blockIdx.x * 256 + threadIdx.x;
    const int nT  = gridDim.x * 256;
    for (int idx = tid; idx < 16384; idx += nT) {
        int kt = (idx >> 12) & 3, nt = (idx >> 9) & 7, lane = (idx >> 3) & 63, j = idx & 7;
        int lr = lane & 15, lg = lane >> 4;
        int ch = nt * 16 + lr, k = kt * 32 + lg * 8 + j;
        float f = (ch < 64) ? w_src[ch * 128 + k] : w_dst[(ch - 64) * 128 + k];
        short hi = f2bf(f);
        pAhi[idx] = hi; pAlo[idx] = f2bf(f - bf2f((unsigned short)hi));
    }
    for (int idx = tid; idx < 8192; idx += nT) {
        int kt = (idx >> 12) & 1, nt = (idx >> 9) & 7, lane = (idx >> 3) & 63, j = idx & 7;
        int lr = lane & 15, lg = lane >> 4;
        int ch = nt * 16 + lr, k = kt * 32 + lg * 8 + j;
        float f = w1[ch * 64 + k];
        short hi = f2bf(f);
        p1hi[idx] = hi; p1lo[idx] = f2bf(f - bf2f((unsigned short)hi));
    }
    for (int idx = tid; idx < 8192; idx += nT) {
        int kt = (idx >> 11) & 3, nt = (idx >> 9) & 3, lane = (idx >> 3) & 63, j = idx & 7;
        int lr = lane & 15, lg = lane >> 4;
        int ch = nt * 16 + lr, k = kt * 32 + lg * 8 + j;
        float f = w2[ch * 128 + k];
        short hi = f2bf(f);
        p2hi[idx] = hi; p2lo[idx] = f2bf(f - bf2f((unsigned short)hi));
    }
    for (int idx = tid; idx < 2048; idx += nT) {
        int nt = (idx >> 9) & 3, lane = (idx >> 3) & 63, j = idx & 7;
        int lr = lane & 15, lg = lane >> 4;
        int ch = nt * 16 + lr, k = lg * 8 + j;
        pE[idx] = f2bf(w_edge[ch * EDD + k]);
    }
    // validity mask for edges 16..31 of each node (bit r = edge 16+r valid)
    for (int n = tid; n < NN; n += nT) {
        const int4* p = (const int4*)&nbr[n * KNB + 16];
        int4 a = p[0], b = p[1], c = p[2], e = p[3];
        unsigned m = 0;
        m |= (a.x >= 0 ? 1u : 0u) << 0;  m |= (a.y >= 0 ? 1u : 0u) << 1;
        m |= (a.z >= 0 ? 1u : 0u) << 2;  m |= (a.w >= 0 ? 1u : 0u) << 3;
        m |= (b.x >= 0 ? 1u : 0u) << 4;  m |= (b.y >= 0 ? 1u : 0u) << 5;
        m |= (b.z >= 0 ? 1u : 0u) << 6;  m |= (b.w >= 0 ? 1u : 0u) << 7;
        m |= (c.x >= 0 ? 1u : 0u) << 8;  m |= (c.y >= 0 ? 1u : 0u) << 9;
        m |= (c.z >= 0 ? 1u : 0u) << 10; m |= (c.w >= 0 ? 1u : 0u) << 11;
        m |= (e.x >= 0 ? 1u : 0u) << 12; m |= (e.y >= 0 ? 1u : 0u) << 13;
        m |= (e.z >= 0 ? 1u : 0u) << 14; m |= (e.w >= 0 ? 1u : 0u) << 15;
        vmsk[n] = m;
    }
}

// ---------------------------------------------------------------------------
// K1 (MFMA): [srcPh|dstf] = x @ [w_src;w_dst].T ; srcPh stored PERMUTED fp16:
// srcPh[node*64 + lr*4 + nt] = src_ch[nt*16+lr]  (row = 128B)
// ---------------------------------------------------------------------------
__global__ __launch_bounds__(256) void k_lin1(
    const float* __restrict__ x, const short* __restrict__ pAhi,
    const short* __restrict__ pAlo, _Float16* __restrict__ srcPh,
    float* __restrict__ dstf)
{
    const int lane = threadIdx.x & 63, wave = threadIdx.x >> 6;
    const int lr = lane & 15, lg = lane >> 4;
    const int nb = blockIdx.x * 64 + wave * 16;
    const bf16x8* Bh = (const bf16x8*)pAhi;
    const bf16x8* Bl = (const bf16x8*)pAlo;
    int row = nb + lr; if (row > NN - 1) row = NN - 1;

    f32x4 acc[8];
    #pragma unroll
    for (int i = 0; i < 8; ++i) acc[i] = (f32x4){0.f, 0.f, 0.f, 0.f};

    #pragma unroll
    for (int kt = 0; kt < 4; ++kt) {
        const float* ap = x + (size_t)row * INC + kt * 32 + lg * 8;
        float4 a0 = *(const float4*)ap, a1 = *(const float4*)(ap + 4);
        float av[8] = {a0.x, a0.y, a0.z, a0.w, a1.x, a1.y, a1.z, a1.w};
        bf16x8 ahi, alo;
        split8(av, ahi, alo);
        #pragma unroll
        for (int nt = 0; nt < 8; ++nt) {
            bf16x8 bh = Bh[(kt * 8 + nt) * 64 + lane];
            bf16x8 bl = Bl[(kt * 8 + nt) * 64 + lane];
            acc[nt] = __builtin_amdgcn_mfma_f32_16x16x32_bf16(ahi, bl, acc[nt], 0, 0, 0);
            acc[nt] = __builtin_amdgcn_mfma_f32_16x16x32_bf16(alo, bh, acc[nt], 0, 0, 0);
            acc[nt] = __builtin_amdgcn_mfma_f32_16x16x32_bf16(ahi, bh, acc[nt], 0, 0, 0);
        }
    }
    #pragma unroll
    for (int nt = 0; nt < 8; ++nt)
        #pragma unroll
        for (int q = 0; q < 4; ++q) {
            int node = nb + lg * 4 + q;
            if (node < NN) {
                float v = acc[nt][q];
                if (nt < 4) srcPh[node * HC + lr * 4 + nt] = (_Float16)v;  // permuted fp16
                else        dstf[node * HC + (nt - 4) * 16 + lr] = v;
            }
        }
}

// ---------------------------------------------------------------------------
// K2 (MFMA, 1 node/wave, VALU-diet + precomputed validity).
// ---------------------------------------------------------------------------
__global__ __launch_bounds__(256) void k_edge_agg_mfma(
    const _Float16* __restrict__ srcPh, const float* __restrict__ dstf,
    const float* __restrict__ edge_attr, const short* __restrict__ pE,
    const int* __restrict__ esrc, const unsigned* __restrict__ vmsk,
    float* __restrict__ outf)
{
    const int lane = threadIdx.x & 63;
    const int wave = threadIdx.x >> 6;
    const int n    = blockIdx.x * 4 + wave;    // 12500 * 4 = 50000
    const int lr = lane & 15, lg = lane >> 4;

    // esrc slots for this lane's 8 edges (2 x int4)
    int4 s0 = *(const int4*)&esrc[n * KNB + lg * 4];
    int4 s1 = *(const int4*)&esrc[n * KNB + 16 + lg * 4];
    unsigned vmask = vmsk[n];                  // wave-uniform broadcast
    float d = dstf[n * HC + lane];

    // B fragments (prepped bf16, raw 16B loads)
    const bf16x8* Bp = (const bf16x8*)pE;
    bf16x8 bfrag[4];
    #pragma unroll
    for (int nt = 0; nt < 4; ++nt) bfrag[nt] = Bp[nt * 64 + lane];

    // attr tile loads (nontemporal; single-use stream)
    const f32x4* ab = (const f32x4*)(edge_attr + (size_t)n * KNB * EDD);
    f32x4 at[4];
    #pragma unroll
    for (int mt = 0; mt < 2; ++mt) {
        int off = ((mt * 16 + lr) * EDD + lg * 8) >> 2;
        at[mt * 2]     = __builtin_nontemporal_load(ab + off);
        at[mt * 2 + 1] = __builtin_nontemporal_load(ab + off + 1);
    }

    // fp16 gathers, 32-bit offsets (idx*64 elements, +lr*4)
    int i0[4] = {s0.x, s0.y, s0.z, s0.w};
    int i1[4] = {s1.x, s1.y, s1.z, s1.w};
    f16x4 xj0[4], xj1[4];
    #pragma unroll
    for (int r = 0; r < 4; ++r)
        xj0[r] = *(const f16x4*)(srcPh + (((unsigned)i0[r] << 6) + lr * 4));
    #pragma unroll
    for (int r = 0; r < 4; ++r)
        xj1[r] = *(const f16x4*)(srcPh + (((unsigned)i1[r] << 6) + lr * 4));

    // attr -> bf16 A-fragments via cvt_pk
    bf16x8 afrag[2];
    #pragma unroll
    for (int mt = 0; mt < 2; ++mt) {
        float av[8] = {at[mt*2][0], at[mt*2][1], at[mt*2][2], at[mt*2][3],
                       at[mt*2+1][0], at[mt*2+1][1], at[mt*2+1][2], at[mt*2+1][3]};
        afrag[mt] = pack8_bf16(av);
    }

    // projection: p[mt][nt][r] = P[16mt + lg*4 + r][16nt + lr]
    f32x4 p[2][4];
    #pragma unroll
    for (int mt = 0; mt < 2; ++mt)
        #pragma unroll
        for (int nt = 0; nt < 4; ++nt) {
            f32x4 z = {0.f, 0.f, 0.f, 0.f};
            p[mt][nt] = __builtin_amdgcn_mfma_f32_16x16x32_bf16(
                afrag[mt], bfrag[nt], z, 0, 0, 0);
        }

    // validity only for edges 16..31 (bit lg*4+r of vmask)
    float vf[4];
    #pragma unroll
    for (int r = 0; r < 4; ++r)
        vf[r] = ((vmask >> (lg * 4 + r)) & 1u) ? 1.f : 0.f;

    // softmax-weighted mean (no max-subtract; eps folded to the end)
    float res[4];
    #pragma unroll
    for (int nt = 0; nt < 4; ++nt) {
        float se = 0.f, ws = 0.f;
        #pragma unroll
        for (int r = 0; r < 4; ++r) {
            float m = fmaxf(p[0][nt][r] + (float)xj0[r][nt], 0.f);
            float t = __expf(m);
            se += t;
            ws = fmaf(m, t, ws);
        }
        #pragma unroll
        for (int r = 0; r < 4; ++r) {
            float m = fmaxf(p[1][nt][r] + (float)xj1[r][nt], 0.f);
            float t = __expf(m) * vf[r];
            se += t;
            ws = fmaf(m, t, ws);
        }
        se += __shfl_xor(se, 16, 64); ws += __shfl_xor(ws, 16, 64);
        se += __shfl_xor(se, 32, 64); ws += __shfl_xor(ws, 32, 64);
        res[nt] = ws * __builtin_amdgcn_rcpf(se + 1e-16f);
    }

    float r01 = (lg & 1) ? res[1] : res[0];
    float r23 = (lg & 1) ? res[3] : res[2];
    float rr  = (lg & 2) ? r23 : r01;
    outf[n * HC + lane] = rr + d + 1e-7f;
}

// ---------------------------------------------------------------------------
// K3 (MFMA): h(bf16) = out @ w1.T  [N,64]->[N,128]  + per-block BN partials.
// ---------------------------------------------------------------------------
__global__ __launch_bounds__(256) void k_lin2(
    const float* __restrict__ outf, const short* __restrict__ p1hi,
    const short* __restrict__ p1lo, unsigned short* __restrict__ hb,
    float* __restrict__ partials)
{
    __shared__ float ps[128 * 16], pq[128 * 16];
    const int t = threadIdx.x;
    const int lane = t & 63, wave = t >> 6;
    const int lr = lane & 15, lg = lane >> 4;
    const int nb = blockIdx.x * 64 + wave * 16;
    const bf16x8* Bh = (const bf16x8*)p1hi;
    const bf16x8* Bl = (const bf16x8*)p1lo;
    int row = nb + lr; if (row > NN - 1) row = NN - 1;

    f32x4 acc[8];
    #pragma unroll
    for (int i = 0; i < 8; ++i) acc[i] = (f32x4){0.f, 0.f, 0.f, 0.f};

    #pragma unroll
    for (int kt = 0; kt < 2; ++kt) {
        const float* ap = outf + (size_t)row * HC + kt * 32 + lg * 8;
        float4 a0 = *(const float4*)ap, a1 = *(const float4*)(ap + 4);
        float av[8] = {a0.x, a0.y, a0.z, a0.w, a1.x, a1.y, a1.z, a1.w};
        bf16x8 ahi, alo;
        split8(av, ahi, alo);
        #pragma unroll
        for (int nt = 0; nt < 8; ++nt) {
            bf16x8 bh = Bh[(kt * 8 + nt) * 64 + lane];
            bf16x8 bl = Bl[(kt * 8 + nt) * 64 + lane];
            acc[nt] = __builtin_amdgcn_mfma_f32_16x16x32_bf16(ahi, bl, acc[nt], 0, 0, 0);
            acc[nt] = __builtin_amdgcn_mfma_f32_16x16x32_bf16(alo, bh, acc[nt], 0, 0, 0);
            acc[nt] = __builtin_amdgcn_mfma_f32_16x16x32_bf16(ahi, bh, acc[nt], 0, 0, 0);
        }
    }

    #pragma unroll
    for (int nt = 0; nt < 8; ++nt) {
        int ch = nt * 16 + lr;
        unsigned pk01, pk23;
        asm("v_cvt_pk_bf16_f32 %0, %1, %2" : "=v"(pk01) : "v"(acc[nt][0]), "v"(acc[nt][1]));
        asm("v_cvt_pk_bf16_f32 %0, %1, %2" : "=v"(pk23) : "v"(acc[nt][2]), "v"(acc[nt][3]));
        unsigned short hv[4] = {(unsigned short)pk01, (unsigned short)(pk01 >> 16),
                                (unsigned short)pk23, (unsigned short)(pk23 >> 16)};
        float s = 0.f, q = 0.f;
        #pragma unroll
        for (int qq = 0; qq < 4; ++qq) {
            int node = nb + lg * 4 + qq;
            float v = acc[nt][qq];
            if (node < NN) {
                hb[(size_t)node * H2C + ch] = hv[qq];
                s += v;
                q += v * v;
            }
        }
        ps[ch * 16 + wave * 4 + lg] = s;
        pq[ch * 16 + wave * 4 + lg] = q;
    }
    __syncthreads();
    if (t < 128) {
        float s = 0.f, q = 0.f;
        #pragma unroll
        for (int i = 0; i < 16; ++i) { s += ps[t * 16 + i]; q += pq[t * 16 + i]; }
        partials[blockIdx.x * 256 + t]       = s;
        partials[blockIdx.x * 256 + 128 + t] = q;
    }
}

// ---------------------------------------------------------------------------
// K4: reduce partials -> BN scale/bias (1024 threads, vectorized).
// ---------------------------------------------------------------------------
__global__ __launch_bounds__(1024) void k_bn_finalize(
    const float* __restrict__ partials, int nblk,
    const float* __restrict__ gamma, const float* __restrict__ beta,
    float* __restrict__ sb)
{
    const int t = threadIdx.x;
    const int f = t & 63;
    const int g = t >> 6;

    float4 acc = {0.f, 0.f, 0.f, 0.f};
    for (int b = g; b < nblk; b += 16) {
        float4 v = *(const float4*)&partials[b * 256 + f * 4];
        acc.x += v.x; acc.y += v.y; acc.z += v.z; acc.w += v.w;
    }

    __shared__ __align__(16) float4 red[16][64];
    red[g][f] = acc;
    __syncthreads();
    #pragma unroll
    for (int s = 8; s > 0; s >>= 1) {
        if (g < s) {
            float4 o = red[g + s][f];
            acc.x += o.x; acc.y += o.y; acc.z += o.z; acc.w += o.w;
            red[g][f] = acc;
        }
        __syncthreads();
    }

    if (t < 128) {
        const float* row = (const float*)&red[0][0];
        float s = row[t];
        float q = row[128 + t];
        float mean = s / (float)NN;
        float var  = q / (float)NN - mean * mean;
        float scale = gamma[t] * rsqrtf(var + 1e-5f);
        float bias  = beta[t] - mean * scale;
        sb[t]       = scale;
        sb[128 + t] = bias;
    }
}

// ---------------------------------------------------------------------------
// K5 (MFMA): out2 = relu(h*scale+bias) @ w2.T  [N,128]->[N,64], h read bf16.
// ---------------------------------------------------------------------------
__global__ __launch_bounds__(256) void k_lin3(
    const unsigned short* __restrict__ hb, const short* __restrict__ p2hi,
    const short* __restrict__ p2lo, const float* __restrict__ sb,
    float* __restrict__ out)
{
    const int lane = threadIdx.x & 63, wave = threadIdx.x >> 6;
    const int lr = lane & 15, lg = lane >> 4;
    const int nb = blockIdx.x * 64 + wave * 16;
    const bf16x8* Bh = (const bf16x8*)p2hi;
    const bf16x8* Bl = (const bf16x8*)p2lo;
    int row = nb + lr; if (row > NN - 1) row = NN - 1;

    f32x4 acc[4];
    #pragma unroll
    for (int i = 0; i < 4; ++i) acc[i] = (f32x4){0.f, 0.f, 0.f, 0.f};

    #pragma unroll
    for (int kt = 0; kt < 4; ++kt) {
        const int k0 = kt * 32 + lg * 8;
        float4 sc0 = *(const float4*)&sb[k0],       sc1 = *(const float4*)&sb[k0 + 4];
        float4 bi0 = *(const float4*)&sb[128 + k0], bi1 = *(const float4*)&sb[128 + k0 + 4];
        u16x8 hv = *(const u16x8*)(hb + (size_t)row * H2C + k0);
        float scv[8] = {sc0.x, sc0.y, sc0.z, sc0.w, sc1.x, sc1.y, sc1.z, sc1.w};
        float biv[8] = {bi0.x, bi0.y, bi0.z, bi0.w, bi1.x, bi1.y, bi1.z, bi1.w};
        float rv[8];
        #pragma unroll
        for (int j = 0; j < 8; ++j) {
            float v = bf2f(hv[j]) * scv[j] + biv[j];
            rv[j] = v > 0.f ? v : 0.f;
        }
        bf16x8 ahi, alo;
        split8(rv, ahi, alo);
        #pragma unroll
        for (int nt = 0; nt < 4; ++nt) {
            bf16x8 bh = Bh[(kt * 4 + nt) * 64 + lane];
            bf16x8 bl = Bl[(kt * 4 + nt) * 64 + lane];
            acc[nt] = __builtin_amdgcn_mfma_f32_16x16x32_bf16(ahi, bl, acc[nt], 0, 0, 0);
            acc[nt] = __builtin_amdgcn_mfma_f32_16x16x32_bf16(alo, bh, acc[nt], 0, 0, 0);
            acc[nt] = __builtin_amdgcn_mfma_f32_16x16x32_bf16(ahi, bh, acc[nt], 0, 0, 0);
        }
    }
    #pragma unroll
    for (int nt = 0; nt < 4; ++nt)
        #pragma unroll
        for (int q = 0; q < 4; ++q) {
            int node = nb + lg * 4 + q;
            if (node < NN) out[node * HC + nt * 16 + lr] = acc[nt][q];
        }
}

// ---------------------------------------------------------------------------
extern "C" void kernel_launch(void* const* d_in, const int* in_sizes, int n_in,
                              void* d_out, int out_size, void* d_ws, size_t ws_size,
                              hipStream_t stream) {
    const float* x         = (const float*)d_in[0];
    const float* edge_attr = (const float*)d_in[1];
    const float* w_src     = (const float*)d_in[2];
    const float* w_dst     = (const float*)d_in[3];
    const float* w_edge    = (const float*)d_in[4];
    const float* w1        = (const float*)d_in[5];
    const float* gamma     = (const float*)d_in[6];
    const float* beta      = (const float*)d_in[7];
    const float* w2        = (const float*)d_in[8];
    const int*   eidx      = (const int*)d_in[9];    // [2][E], row 0 = src
    const int*   nbr       = (const int*)d_in[10];   // [N][K]

    float* ws   = (float*)d_ws;
    _Float16* srcPh = (_Float16*)ws;           // N*64 fp16 (permuted)
    float* dstf = ws + 3200000;                // N*64
    float* outf = ws + 6400000;                // N*64
    unsigned short* hb = (unsigned short*)(ws + 9600000);   // N*128 bf16
    float* part = ws + 16000000;               // NBLK*256
    float* sb   = ws + 16250000;               // 256
    short* sp   = (short*)(ws + 16300000);
    short* pAhi = sp;                          // 16384 shorts
    short* pAlo = sp + 16384;
    short* p1hi = sp + 32768;                  // 8192
    short* p1lo = sp + 40960;
    short* p2hi = sp + 49152;                  // 8192
    short* p2lo = sp + 57344;
    short* pE   = sp + 65536;                  // 2048
    unsigned* vmsk = (unsigned*)(ws + 16400000);  // N u32

    hipLaunchKernelGGL(k_prep,          dim3(64),    dim3(256),  0, stream,
                       w_src, w_dst, w1, w2, w_edge, nbr,
                       pAhi, pAlo, p1hi, p1lo, p2hi, p2lo, pE, vmsk);
    hipLaunchKernelGGL(k_lin1,          dim3(NBLK),  dim3(256),  0, stream,
                       x, pAhi, pAlo, srcPh, dstf);
    hipLaunchKernelGGL(k_edge_agg_mfma, dim3(12500), dim3(256),  0, stream,
                       srcPh, dstf, edge_attr, pE, eidx, vmsk, outf);
    hipLaunchKernelGGL(k_lin2,          dim3(NBLK),  dim3(256),  0, stream,
                       outf, p1hi, p1lo, hb, part);
    hipLaunchKernelGGL(k_bn_finalize,   dim3(1),     dim3(1024), 0, stream,
                       part, NBLK, gamma, beta, sb);
    hipLaunchKernelGGL(k_lin3,          dim3(NBLK),  dim3(256),  0, stream,
                       hb, p2hi, p2lo, sb, (float*)d_out);
}